// Round 2
// baseline (338.906 us; speedup 1.0000x reference)
//
#include <hip/hip_runtime.h>
#include <stdint.h>

#define B_   32
#define CIN  64
#define COUT 64
#define H_   128
#define W_   128
#define HP   130
#define WP   130

typedef __bf16 bf16x8 __attribute__((ext_vector_type(8)));
typedef float  f32x4  __attribute__((ext_vector_type(4)));

__device__ inline unsigned short f2bf(float f) {
  union { float f; unsigned u; } uf; uf.f = f;
  unsigned u = uf.u;
  unsigned r = 0x7FFFu + ((u >> 16) & 1u);
  return (unsigned short)((u + r) >> 16);
}

// Wb[b][p][cout][cin] = bf16(W0 + cov[b]*W1), p = kh*3+kw
__global__ __launch_bounds__(256) void prep_w(const float* __restrict__ W0,
                                              const float* __restrict__ W1,
                                              const float* __restrict__ cov,
                                              unsigned short* __restrict__ Wb) {
  int g  = blockIdx.x * 256 + threadIdx.x;   // [0, 32*9*64*64)
  int ci = g & 63;
  int co = (g >> 6) & 63;
  int v  = g >> 12;                          // b*9 + p, [0,288)
  int b  = v / 9;
  int p  = v - b * 9;
  int widx = (co * CIN + ci) * 9 + p;
  float val = W0[widx] + cov[b] * W1[widx];
  Wb[g] = f2bf(val);
}

// zero the halo of Xt: row h'=0 (8320), row h'=129 (8320), cols w'={0,129}
// for h'=1..128 (16384). Total 33024 per batch = 129 blocks x 256 exactly.
__global__ __launch_bounds__(256) void zero_pad(unsigned short* __restrict__ Xt) {
  int b = blockIdx.y;
  int i = blockIdx.x * 256 + threadIdx.x;    // [0, 33024)
  size_t base = (size_t)b * HP * WP * 64;
  if (i < 8320) {                            // row h'=0
    Xt[base + i] = 0;
  } else if (i < 16640) {                    // row h'=129
    Xt[base + (size_t)129 * WP * 64 + (i - 8320)] = 0;
  } else {
    int j = i - 16640;                       // [0, 16384): cols w'=0,129
    int hh   = 1 + (j >> 7);                 // 1..128
    int side = (j >> 6) & 1;
    int cc   = j & 63;
    Xt[base + ((size_t)hh * WP + side * 129) * 64 + cc] = 0;
  }
}

// Xt[b][h'][w'][ci] bf16, h'=h+1, w'=w+1, ci-blocks XOR-swizzled by (w'&7)
__global__ __launch_bounds__(256) void prep_x(const float* __restrict__ X,
                                              unsigned short* __restrict__ Xt) {
  __shared__ unsigned short T[64][66];
  int bid = blockIdx.x;           // b*256 + h*2 + wt
  int wt = bid & 1;
  int h  = (bid >> 1) & 127;
  int b  = bid >> 8;
  int t  = threadIdx.x;
  int wlane = t & 63;
  int g0 = t >> 6;                // wave id 0..3
  int w0 = wt * 64;

  const float* src = X + (((size_t)b * CIN) * H_ + h) * W_ + w0 + wlane;
  for (int ci = g0; ci < 64; ci += 4) {
    T[ci][wlane] = f2bf(src[(size_t)ci * (H_ * W_)]);
  }
  __syncthreads();

  int ci = t & 63;
  for (int wi = g0; wi < 64; wi += 4) {
    int wpp = w0 + wi + 1;
    int blk = (ci >> 3) ^ (wpp & 7);
    size_t base = (((size_t)b * HP + (h + 1)) * WP + wpp) * 64;
    Xt[base + blk * 8 + (ci & 7)] = T[ci][wi];
  }
}

// main: block = (batch b, 2 output rows), 64 cout x 256 pixels, 4 waves
__global__ __launch_bounds__(256, 2) void conv_main(
    const unsigned short* __restrict__ Xt,
    const unsigned short* __restrict__ Wb,
    float* __restrict__ out) {
  __shared__ __align__(16) unsigned short Xs[4 * WP * 64];  // 66,560 B

  int tile = blockIdx.x;          // b*64 + th
  int b  = tile >> 6;
  int h0 = (tile & 63) * 2;
  int t  = threadIdx.x;
  int w  = t >> 6;                // wave 0..3
  int l  = t & 63;

  // flat contiguous stage: Xt rows h0..h0+3 (already padded+swizzled)
  {
    const int4* s4 = (const int4*)(Xt + ((size_t)b * HP + h0) * WP * 64);
    int4* d4 = (int4*)Xs;
    for (int k = t; k < 4160; k += 256) d4[k] = s4[k];
  }
  __syncthreads();

  int lh = l & 15;
  int q  = l >> 4;

  f32x4 acc[4][4];
  #pragma unroll
  for (int i = 0; i < 4; i++)
    #pragma unroll
    for (int j = 0; j < 4; j++) acc[i][j] = (f32x4){0.f, 0.f, 0.f, 0.f};

  int rbase[4], cbase[4];
  #pragma unroll
  for (int nt = 0; nt < 4; nt++) {
    int p = w * 64 + nt * 16 + lh;    // pixel in the 2x128 tile
    rbase[nt] = p >> 7;
    cbase[nt] = p & 127;
  }

  const unsigned short* wbase = Wb + (size_t)b * 9 * 64 * 64;

  for (int kh = 0; kh < 3; kh++) {
    for (int kw = 0; kw < 3; kw++) {
      const unsigned short* wk = wbase + (kh * 3 + kw) * 64 * 64;
      bf16x8 af[2][4], bfr[2][4];
      #pragma unroll
      for (int ck = 0; ck < 2; ck++)
        #pragma unroll
        for (int mt = 0; mt < 4; mt++)
          af[ck][mt] = *(const bf16x8*)(wk + (mt * 16 + lh) * 64 + ck * 32 + q * 8);
      #pragma unroll
      for (int ck = 0; ck < 2; ck++)
        #pragma unroll
        for (int nt = 0; nt < 4; nt++) {
          int r = rbase[nt] + kh;
          int c = cbase[nt] + kw;
          int blk = (ck * 4 + q) ^ (c & 7);   // undo XOR swizzle
          bfr[ck][nt] = *(const bf16x8*)(Xs + (r * WP + c) * 64 + blk * 8);
        }
      #pragma unroll
      for (int ck = 0; ck < 2; ck++)
        #pragma unroll
        for (int mt = 0; mt < 4; mt++)
          #pragma unroll
          for (int nt = 0; nt < 4; nt++)
            acc[mt][nt] = __builtin_amdgcn_mfma_f32_16x16x32_bf16(
                af[ck][mt], bfr[ck][nt], acc[mt][nt], 0, 0, 0);
    }
  }

  // epilogue: C/D layout row=(lane>>4)*4+reg (cout), col=lane&15 (pixel)
  #pragma unroll
  for (int mt = 0; mt < 4; mt++) {
    int coutb = mt * 16 + q * 4;
    #pragma unroll
    for (int nt = 0; nt < 4; nt++) {
      int oh = h0 + rbase[nt];
      int ow = cbase[nt];
      #pragma unroll
      for (int r = 0; r < 4; r++) {
        int cout = coutb + r;
        out[(((size_t)b * COUT + cout) * H_ + oh) * W_ + ow] = acc[mt][nt][r];
      }
    }
  }
}

extern "C" void kernel_launch(void* const* d_in, const int* in_sizes, int n_in,
                              void* d_out, int out_size, void* d_ws, size_t ws_size,
                              hipStream_t stream) {
  const float* x   = (const float*)d_in[0];
  const float* cov = (const float*)d_in[1];
  const float* W0  = (const float*)d_in[2];
  const float* W1  = (const float*)d_in[3];
  float* out = (float*)d_out;

  unsigned short* Xt = (unsigned short*)d_ws;                 // 69,222,400 B
  unsigned short* Wb = (unsigned short*)((char*)d_ws + (size_t)B_ * HP * WP * 64 * 2);

  prep_w  <<<dim3(4608),     dim3(256), 0, stream>>>(W0, W1, cov, Wb);
  zero_pad<<<dim3(129, 32),  dim3(256), 0, stream>>>(Xt);
  prep_x  <<<dim3(8192),     dim3(256), 0, stream>>>(x, Xt);
  conv_main<<<dim3(2048),    dim3(256), 0, stream>>>(Xt, Wb, out);
}

// Round 3
// 302.673 us; speedup vs baseline: 1.1197x; 1.1197x over previous
//
#include <hip/hip_runtime.h>
#include <stdint.h>

#define B_   32
#define CIN  64
#define COUT 64
#define H_   128
#define W_   128
#define WP   130

typedef __bf16 bf16x8 __attribute__((ext_vector_type(8)));
typedef float  f32x4  __attribute__((ext_vector_type(4)));

__device__ inline unsigned int f2bf(float f) {
  union { float f; unsigned u; } uf; uf.f = f;
  unsigned u = uf.u;
  unsigned r = 0x7FFFu + ((u >> 16) & 1u);
  return (u + r) >> 16;
}

// Wb[b][p][cout][cin] = bf16(W0 + cov[b]*W1), p = kh*3+kw
__global__ __launch_bounds__(256) void prep_w(const float* __restrict__ W0,
                                              const float* __restrict__ W1,
                                              const float* __restrict__ cov,
                                              unsigned short* __restrict__ Wb) {
  int g  = blockIdx.x * 256 + threadIdx.x;   // [0, 32*9*64*64)
  int ci = g & 63;
  int co = (g >> 6) & 63;
  int v  = g >> 12;                          // b*9 + p
  int b  = v / 9;
  int p  = v - b * 9;
  int widx = (co * CIN + ci) * 9 + p;
  float val = W0[widx] + cov[b] * W1[widx];
  Wb[g] = (unsigned short)f2bf(val);
}

// fused: transpose/convert/pad staging + implicit-GEMM MFMA conv
// block = (batch b, 2 output rows); LDS Xs[r][w'][ci] with ci-octet XOR swizzle
__global__ __launch_bounds__(256, 2) void conv_fused(
    const float* __restrict__ X,
    const unsigned short* __restrict__ Wb,
    float* __restrict__ out) {
  __shared__ __align__(16) unsigned short Xs[4 * WP * 64];  // 66,560 B

  int tile = blockIdx.x;          // b*64 + th
  int b  = tile >> 6;
  int h0 = (tile & 63) * 2;
  int t  = threadIdx.x;
  int wv = t >> 6;                // wave 0..3 → staging row r
  int l  = t & 63;

  // ---- staging: wave wv fills LDS row r=wv (input row ih = h0-1+wv) ----
  unsigned short* dst_row = Xs + wv * WP * 64;

  // halo columns w'=0 and w'=129: 64+64 shorts = 32+32 uints per row
  {
    unsigned int* d32 = (unsigned int*)dst_row;
    if (l < 32) d32[l] = 0u;                        // w'=0
    else        d32[129 * 32 + (l - 32)] = 0u;      // w'=129
  }

  int ih = h0 - 1 + wv;
  if (ih < 0 || ih > 127) {
    // out-of-range input row: zero interior w'=1..128 (8192 shorts = 1024 int4)
    int4 z = {0, 0, 0, 0};
    int4* d = (int4*)(dst_row + 64);
    #pragma unroll
    for (int k = 0; k < 16; k++) d[k * 64 + l] = z;
  } else {
    const float* src = X + (((size_t)b * CIN) * H_ + ih) * W_;
    int w1 = l + 1, w2 = l + 65;                    // this lane's two w' slots
    unsigned short* p1 = dst_row + w1 * 64;
    unsigned short* p2 = dst_row + w2 * 64;
    #pragma unroll 4
    for (int ci = 0; ci < 64; ci += 2) {
      const float* s0 = src + (size_t)ci * (H_ * W_);
      float a0 = s0[l];
      float a1 = s0[H_ * W_ + l];
      float b0 = s0[64 + l];
      float b1 = s0[H_ * W_ + 64 + l];
      unsigned int lo = f2bf(a0) | (f2bf(a1) << 16);
      unsigned int hi = f2bf(b0) | (f2bf(b1) << 16);
      int blk1 = (ci >> 3) ^ (w1 & 7);
      int blk2 = (ci >> 3) ^ (w2 & 7);
      *(unsigned int*)(p1 + blk1 * 8 + (ci & 7)) = lo;
      *(unsigned int*)(p2 + blk2 * 8 + (ci & 7)) = hi;
    }
  }
  __syncthreads();

  // ---- compute: 64 cout x 256 pixels, 4 waves ----
  int lh = l & 15;
  int q  = l >> 4;

  f32x4 acc[4][4];
  #pragma unroll
  for (int i = 0; i < 4; i++)
    #pragma unroll
    for (int j = 0; j < 4; j++) acc[i][j] = (f32x4){0.f, 0.f, 0.f, 0.f};

  int rbase[4], cbase[4];
  #pragma unroll
  for (int nt = 0; nt < 4; nt++) {
    int p = wv * 64 + nt * 16 + lh;   // pixel in the 2x128 tile
    rbase[nt] = p >> 7;
    cbase[nt] = p & 127;
  }

  const unsigned short* wbase = Wb + (size_t)b * 9 * 64 * 64;

  for (int kh = 0; kh < 3; kh++) {
    for (int kw = 0; kw < 3; kw++) {
      const unsigned short* wk = wbase + (kh * 3 + kw) * 64 * 64;
      bf16x8 af[2][4], bfr[2][4];
      #pragma unroll
      for (int ck = 0; ck < 2; ck++)
        #pragma unroll
        for (int mt = 0; mt < 4; mt++)
          af[ck][mt] = *(const bf16x8*)(wk + (mt * 16 + lh) * 64 + ck * 32 + q * 8);
      #pragma unroll
      for (int ck = 0; ck < 2; ck++)
        #pragma unroll
        for (int nt = 0; nt < 4; nt++) {
          int r = rbase[nt] + kh;
          int c = cbase[nt] + kw;
          int blk = (ck * 4 + q) ^ (c & 7);   // undo XOR swizzle
          bfr[ck][nt] = *(const bf16x8*)(Xs + (r * WP + c) * 64 + blk * 8);
        }
      #pragma unroll
      for (int ck = 0; ck < 2; ck++)
        #pragma unroll
        for (int mt = 0; mt < 4; mt++)
          #pragma unroll
          for (int nt = 0; nt < 4; nt++)
            acc[mt][nt] = __builtin_amdgcn_mfma_f32_16x16x32_bf16(
                af[ck][mt], bfr[ck][nt], acc[mt][nt], 0, 0, 0);
    }
  }

  // epilogue: C/D layout row=(lane>>4)*4+reg (cout), col=lane&15 (pixel)
  #pragma unroll
  for (int mt = 0; mt < 4; mt++) {
    int coutb = mt * 16 + q * 4;
    #pragma unroll
    for (int nt = 0; nt < 4; nt++) {
      int oh = h0 + rbase[nt];
      int ow = cbase[nt];
      #pragma unroll
      for (int r = 0; r < 4; r++) {
        int cout = coutb + r;
        out[(((size_t)b * COUT + cout) * H_ + oh) * W_ + ow] = acc[mt][nt][r];
      }
    }
  }
}

extern "C" void kernel_launch(void* const* d_in, const int* in_sizes, int n_in,
                              void* d_out, int out_size, void* d_ws, size_t ws_size,
                              hipStream_t stream) {
  const float* x   = (const float*)d_in[0];
  const float* cov = (const float*)d_in[1];
  const float* W0  = (const float*)d_in[2];
  const float* W1  = (const float*)d_in[3];
  float* out = (float*)d_out;

  unsigned short* Wb = (unsigned short*)d_ws;   // 32*9*64*64*2 = 4,718,592 B

  prep_w   <<<dim3(4608), dim3(256), 0, stream>>>(W0, W1, cov, Wb);
  conv_fused<<<dim3(2048), dim3(256), 0, stream>>>(x, Wb, out);
}